// Round 1
// baseline (27211.273 us; speedup 1.0000x reference)
//
#include <hip/hip_runtime.h>
#include <math.h>

#define D_MODEL 1024
#define NHEAD 16
#define HEADD 64
#define NLAYER 8
#define BATCH 2
#define SEQ 1024
#define VOCAB 50257
#define ROWS (BATCH*SEQ)   // 2048

// ---------------- embedding: x = tok_emb[idx] + pos_emb[t] ----------------
__global__ void embed_kernel(const int* __restrict__ idx, const float* __restrict__ tok,
                             const float* __restrict__ pos, float* __restrict__ x) {
    int row = blockIdx.x;            // 0..ROWS-1,  row = b*SEQ + t
    int t = row % SEQ;
    int v = idx[row];
    const float* tr = tok + (size_t)v * D_MODEL;
    const float* pr = pos + (size_t)t * D_MODEL;
    float* xr = x + (size_t)row * D_MODEL;
    for (int i = threadIdx.x; i < D_MODEL; i += blockDim.x)
        xr[i] = tr[i] + pr[i];
}

// ---------------- layernorm: one block (256 thr) per row ----------------
__global__ void ln_kernel(const float* __restrict__ x, const float* __restrict__ g,
                          const float* __restrict__ b, float* __restrict__ y) {
    __shared__ float sh1[4], sh2[4];
    int row = blockIdx.x;
    const float* xr = x + (size_t)row * D_MODEL;
    float* yr = y + (size_t)row * D_MODEL;
    float s = 0.f, sq = 0.f;
    for (int i = threadIdx.x; i < D_MODEL; i += 256) {
        float v = xr[i]; s += v; sq += v * v;
    }
    #pragma unroll
    for (int off = 32; off; off >>= 1) {
        s  += __shfl_xor(s,  off, 64);
        sq += __shfl_xor(sq, off, 64);
    }
    int w = threadIdx.x >> 6, lane = threadIdx.x & 63;
    if (lane == 0) { sh1[w] = s; sh2[w] = sq; }
    __syncthreads();
    s  = sh1[0] + sh1[1] + sh1[2] + sh1[3];
    sq = sh2[0] + sh2[1] + sh2[2] + sh2[3];
    float mean = s * (1.f / D_MODEL);
    float var  = sq * (1.f / D_MODEL) - mean * mean;
    float inv  = rsqrtf(var + 1e-5f);
    for (int i = threadIdx.x; i < D_MODEL; i += 256)
        yr[i] = (xr[i] - mean) * inv * g[i] + b[i];
}

// ---------------- tiled SGEMM: C[M,N] = A[M,K] @ B (+bias)(gelu)(+res) ----------------
// TRANSB=false: B is [K,N] row-major.  TRANSB=true: B is [N,K] row-major (use B^T).
// M must be a multiple of 64 (true here: M=2048). K must be a multiple of 16.
#define BM 64
#define BN 64
#define BKK 16

template<bool TRANSB>
__global__ void gemm_kernel(const float* __restrict__ A, const float* __restrict__ B,
                            const float* __restrict__ bias, const float* __restrict__ res,
                            float* __restrict__ C, int M, int N, int K, int dogelu) {
    __shared__ float As[BKK][BM + 1];
    __shared__ float Bs[BKK][BN + 1];
    int tid = threadIdx.x;              // 0..255
    int tx = tid & 15, ty = tid >> 4;   // 16x16 thread tile, each does 4x4
    int m0 = blockIdx.y * BM;
    int n0 = blockIdx.x * BN;
    float acc[4][4] = {};
    for (int k0 = 0; k0 < K; k0 += BKK) {
        #pragma unroll
        for (int i = 0; i < 4; i++) {           // A tile: 64 rows x 16 k
            int e = tid + 256 * i;
            int r = e >> 4, c = e & 15;
            As[c][r] = A[(size_t)(m0 + r) * K + k0 + c];
        }
        #pragma unroll
        for (int i = 0; i < 4; i++) {           // B tile: 16 k x 64 n
            int e = tid + 256 * i;
            if (!TRANSB) {
                int r = e >> 6, c = e & 63;
                int n = n0 + c;
                Bs[r][c] = (n < N) ? B[(size_t)(k0 + r) * N + n] : 0.f;
            } else {
                int c = e >> 4, kk = e & 15;
                int n = n0 + c;
                Bs[kk][c] = (n < N) ? B[(size_t)n * K + k0 + kk] : 0.f;
            }
        }
        __syncthreads();
        #pragma unroll
        for (int kk = 0; kk < BKK; kk++) {
            float a[4], bv[4];
            #pragma unroll
            for (int i = 0; i < 4; i++) a[i]  = As[kk][ty * 4 + i];
            #pragma unroll
            for (int j = 0; j < 4; j++) bv[j] = Bs[kk][tx * 4 + j];
            #pragma unroll
            for (int i = 0; i < 4; i++)
                #pragma unroll
                for (int j = 0; j < 4; j++)
                    acc[i][j] += a[i] * bv[j];
        }
        __syncthreads();
    }
    #pragma unroll
    for (int i = 0; i < 4; i++) {
        int m = m0 + ty * 4 + i;
        #pragma unroll
        for (int j = 0; j < 4; j++) {
            int n = n0 + tx * 4 + j;
            if (n < N) {
                float v = acc[i][j];
                if (bias) v += bias[n];
                if (dogelu) v = 0.5f * v * (1.f + erff(v * 0.70710678118654752f));
                if (res) v += res[(size_t)m * N + n];
                C[(size_t)m * N + n] = v;
            }
        }
    }
}

// ---------------- attention: one wave (64 thr) per (b, h, query t) ----------------
// qkv layout: [ROWS, 3*D_MODEL]; q at col h*64, k at D_MODEL + h*64, v at 2*D_MODEL + h*64
__global__ void attn_kernel(const float* __restrict__ qkv, float* __restrict__ out) {
    __shared__ float q_s[HEADD];
    __shared__ float sc[SEQ];
    int t  = blockIdx.x;
    int bh = blockIdx.y;
    int b  = bh / NHEAD, h = bh % NHEAD;
    int tid = threadIdx.x;              // 0..63
    const size_t stride = 3 * D_MODEL;
    q_s[tid] = qkv[((size_t)(b * SEQ + t)) * stride + h * HEADD + tid];
    __syncthreads();
    const float scale = 0.125f;         // 1/sqrt(64)
    for (int j = tid; j <= t; j += 64) {
        const float* krow = qkv + ((size_t)(b * SEQ + j)) * stride + D_MODEL + h * HEADD;
        float d = 0.f;
        #pragma unroll
        for (int e = 0; e < HEADD; e++) d += q_s[e] * krow[e];
        sc[j] = d * scale;
    }
    __syncthreads();
    float m = -1e30f;
    for (int j = tid; j <= t; j += 64) m = fmaxf(m, sc[j]);
    #pragma unroll
    for (int off = 32; off; off >>= 1) m = fmaxf(m, __shfl_xor(m, off, 64));
    float s = 0.f;
    for (int j = tid; j <= t; j += 64) { float p = expf(sc[j] - m); sc[j] = p; s += p; }
    #pragma unroll
    for (int off = 32; off; off >>= 1) s += __shfl_xor(s, off, 64);
    __syncthreads();
    float inv = 1.f / s;
    float acc = 0.f;                    // lane = head dim d
    for (int j = 0; j <= t; j++) {
        const float* vrow = qkv + ((size_t)(b * SEQ + j)) * stride + 2 * D_MODEL + h * HEADD;
        acc += sc[j] * vrow[tid];
    }
    out[((size_t)(b * SEQ + t)) * D_MODEL + h * HEADD + tid] = acc * inv;
}

// ---------------- loss: per-row logsumexp, atomicAdd mean into *loss ----------------
__global__ void loss_kernel(const float* __restrict__ logits, const int* __restrict__ tgt,
                            float* __restrict__ loss) {
    __shared__ float sh[4];
    int row = blockIdx.x;
    const float* lr = logits + (size_t)row * VOCAB;
    float m = -1e30f;
    for (int j = threadIdx.x; j < VOCAB; j += 256) m = fmaxf(m, lr[j]);
    #pragma unroll
    for (int off = 32; off; off >>= 1) m = fmaxf(m, __shfl_xor(m, off, 64));
    int w = threadIdx.x >> 6, lane = threadIdx.x & 63;
    if (lane == 0) sh[w] = m;
    __syncthreads();
    m = fmaxf(fmaxf(sh[0], sh[1]), fmaxf(sh[2], sh[3]));
    float s = 0.f;
    for (int j = threadIdx.x; j < VOCAB; j += 256) s += expf(lr[j] - m);
    #pragma unroll
    for (int off = 32; off; off >>= 1) s += __shfl_xor(s, off, 64);
    __syncthreads();            // everyone done reading sh for max
    if (lane == 0) sh[w] = s;
    __syncthreads();
    s = sh[0] + sh[1] + sh[2] + sh[3];
    if (threadIdx.x == 0) {
        float lse = logf(s) + m;
        float li = lr[tgt[row]];
        atomicAdd(loss, (lse - li) * (1.f / ROWS));
    }
}

extern "C" void kernel_launch(void* const* d_in, const int* in_sizes, int n_in,
                              void* d_out, int out_size, void* d_ws, size_t ws_size,
                              hipStream_t stream) {
    const int*   idx     = (const int*)d_in[0];
    const int*   targets = (const int*)d_in[1];
    const float* tok     = (const float*)d_in[2];
    const float* pos     = (const float*)d_in[3];
    const float* ln1_g   = (const float*)d_in[4];
    const float* ln1_b   = (const float*)d_in[5];
    const float* qkv_w   = (const float*)d_in[6];
    const float* proj_w  = (const float*)d_in[7];
    const float* ln2_g   = (const float*)d_in[8];
    const float* ln2_b   = (const float*)d_in[9];
    const float* w1      = (const float*)d_in[10];
    const float* b1      = (const float*)d_in[11];
    const float* w2      = (const float*)d_in[12];
    const float* b2      = (const float*)d_in[13];
    const float* lnf_g   = (const float*)d_in[14];
    const float* lnf_b   = (const float*)d_in[15];
    float* out = (float*)d_out;
    float* ws  = (float*)d_ws;

    // workspace layout (floats)
    float* x    = ws;                                  // 2048*1024  =  2.10M
    float* h    = x    + (size_t)ROWS * D_MODEL;       // 2048*1024
    float* qkv  = h    + (size_t)ROWS * D_MODEL;       // 2048*3072
    float* attn = qkv  + (size_t)ROWS * 3 * D_MODEL;   // 2048*1024
    float* mid  = attn + (size_t)ROWS * D_MODEL;       // 2048*4096
    // total: 20.97M floats = 83.9 MB

    embed_kernel<<<ROWS, 256, 0, stream>>>(idx, tok, pos, x);

    for (int l = 0; l < NLAYER; l++) {
        ln_kernel<<<ROWS, 256, 0, stream>>>(x, ln1_g + l * D_MODEL, ln1_b + l * D_MODEL, h);

        dim3 gq(3 * D_MODEL / BN, ROWS / BM);
        gemm_kernel<false><<<gq, 256, 0, stream>>>(
            h, qkv_w + (size_t)l * D_MODEL * 3 * D_MODEL, nullptr, nullptr,
            qkv, ROWS, 3 * D_MODEL, D_MODEL, 0);

        attn_kernel<<<dim3(SEQ, BATCH * NHEAD), 64, 0, stream>>>(qkv, attn);

        dim3 gp(D_MODEL / BN, ROWS / BM);
        gemm_kernel<false><<<gp, 256, 0, stream>>>(
            attn, proj_w + (size_t)l * D_MODEL * D_MODEL, nullptr, x,
            x, ROWS, D_MODEL, D_MODEL, 0);

        ln_kernel<<<ROWS, 256, 0, stream>>>(x, ln2_g + l * D_MODEL, ln2_b + l * D_MODEL, h);

        dim3 gf1(4 * D_MODEL / BN, ROWS / BM);
        gemm_kernel<false><<<gf1, 256, 0, stream>>>(
            h, w1 + (size_t)l * D_MODEL * 4 * D_MODEL, b1 + (size_t)l * 4 * D_MODEL, nullptr,
            mid, ROWS, 4 * D_MODEL, D_MODEL, 1);

        gemm_kernel<false><<<gp, 256, 0, stream>>>(
            mid, w2 + (size_t)l * 4 * D_MODEL * D_MODEL, b2 + (size_t)l * D_MODEL, x,
            x, ROWS, D_MODEL, 4 * D_MODEL, 0);
    }

    ln_kernel<<<ROWS, 256, 0, stream>>>(x, lnf_g, lnf_b, h);

    dim3 gl((VOCAB + BN - 1) / BN, ROWS / BM);
    gemm_kernel<true><<<gl, 256, 0, stream>>>(
        h, tok, nullptr, nullptr, out, ROWS, VOCAB, D_MODEL, 0);

    hipMemsetAsync(out + (size_t)ROWS * VOCAB, 0, sizeof(float), stream);
    loss_kernel<<<ROWS, 256, 0, stream>>>(out, targets, out + (size_t)ROWS * VOCAB);
}